// Round 1
// baseline (701.679 us; speedup 1.0000x reference)
//
#include <hip/hip_runtime.h>
#include <hip/hip_bf16.h>

// SpikeFP32Embedding: out[b,s,e,bit] = weight_pulse[token_ids[b,s], e, bit]
// token_ids: [8, 2048] int32  (in_sizes[0] = 16384)
// weight_pulse: [32768, 128, 32] float32 (in_sizes[1] = 134217728)
// out: [8, 2048, 128, 32] float32 (out_size = 67108864)
//
// Each row is 4096 contiguous floats (16 KiB) = 1024 float4.
// One block per token; 256 threads; 4 float4 per thread.

__global__ __launch_bounds__(256) void spike_embed_gather(
    const int* __restrict__ tok,
    const float4* __restrict__ w,
    float4* __restrict__ out)
{
    const int t = blockIdx.x;                 // token index [0, 16384)
    const int row = tok[t];                   // block-uniform -> s_load + broadcast
    const float4* __restrict__ src = w + (size_t)row * 1024;
    float4* __restrict__ dst = out + (size_t)t * 1024;
    const int i = threadIdx.x;
#pragma unroll
    for (int k = 0; k < 4; ++k) {
        dst[i + k * 256] = src[i + k * 256];
    }
}

extern "C" void kernel_launch(void* const* d_in, const int* in_sizes, int n_in,
                              void* d_out, int out_size, void* d_ws, size_t ws_size,
                              hipStream_t stream) {
    const int* tok = (const int*)d_in[0];
    const float4* w = (const float4*)d_in[1];
    float4* out = (float4*)d_out;
    const int n_tokens = in_sizes[0];         // 16384
    spike_embed_gather<<<n_tokens, 256, 0, stream>>>(tok, w, out);
}